// Round 7
// baseline (1419.850 us; speedup 1.0000x reference)
//
#include <hip/hip_runtime.h>

#define BATCH 32768
#define NVEC  4096
#define EDIM  256
#define KNN   20

#define TS 128               // samples per gemm block
#define TC 128               // codes per gemm block
#define NCT (NVEC/TC)        // 32 code tiles
#define NST (BATCH/TS)       // 256 sample tiles
#define GGRID (NST*NCT)      // 8192 blocks
#define NKK 8                // K-steps of 32
#define MARGIN 2.0f          // > 2 * worst-case bf16 dot error (~0.8)
#define FINF   3.4e38f

typedef short          s16x8 __attribute__((ext_vector_type(8)));
typedef unsigned short u16x8 __attribute__((ext_vector_type(8)));
typedef float          f32x4 __attribute__((ext_vector_type(4)));

__device__ __forceinline__ unsigned short f2bf(float f) {
  unsigned int u = __float_as_uint(f);
  u += 0x7fffu + ((u >> 16) & 1u);   // RNE; inputs finite
  return (unsigned short)(u >> 16);
}

// monotone float->uint encoding: order-preserving over all finite floats
__device__ __forceinline__ unsigned int fenc(float f) {
  unsigned int u = __float_as_uint(f);
  return (u & 0x80000000u) ? ~u : (u | 0x80000000u);
}

// fp32 k-ascending dot — EXACT source pattern of the passing kernels
// (same compiler contraction => same rounding class as the reference).
__device__ __forceinline__ float dot_np(const float4* __restrict__ xq,
                                        const float4* __restrict__ wq) {
  float d = 0.f;
  for (int k = 0; k < EDIM / 4; k++) {
    float4 a4 = xq[k], b4 = wq[k];
    d += a4.x * b4.x;
    d += a4.y * b4.y;
    d += a4.z * b4.z;
    d += a4.w * b4.w;
  }
  return d;
}

__device__ __forceinline__ void gload16(const unsigned short* g, unsigned short* l) {
  __builtin_amdgcn_global_load_lds(
      (const __attribute__((address_space(1))) unsigned int*)g,
      (__attribute__((address_space(3))) unsigned int*)l, 16, 0, 0);
}

// streaming top-3 insert (values) + top-2 rows, branchless.
// strict '<': earlier-inserted row wins ties (set semantics safe either way).
#define INS3(v_, q_) { \
  float om1_ = m1, om2_ = m2; \
  m3 = fminf(m3, fmaxf(om2_, (v_))); \
  m2 = fminf(om2_, fmaxf(om1_, (v_))); \
  bool lt1_ = (v_) < om1_, lt2_ = (v_) < om2_; \
  r2 = lt1_ ? r1 : (lt2_ ? (q_) : r2); \
  r1 = lt1_ ? (q_) : r1; \
  m1 = fminf(om1_, (v_)); \
}

// fp32 row-major [R][256] -> bf16 fragment-order tiles.
// chunk c = ((rowtile*8 + kk)*8 + g): 1KB holding rows rowtile*128+g*16+lm,
// cols kk*32+lq*8 (8 bf16 per lane, lane = lq*16+lm). One wave per chunk.
__global__ __launch_bounds__(256)
void k_tilecvt(const float* __restrict__ src, unsigned short* __restrict__ dst) {
  const int lane = threadIdx.x & 63, wv = threadIdx.x >> 6;
  const int lm = lane & 15, lq = lane >> 4;
  const int c = blockIdx.x * 4 + wv;
  const int rt = c >> 6, kk = (c >> 3) & 7, g = c & 7;
  const int row = rt * 128 + g * 16 + lm;
  const float* p = src + (size_t)row * EDIM + kk * 32 + lq * 8;
  float4 a = ((const float4*)p)[0], b = ((const float4*)p)[1];
  u16x8 o;
  o[0] = f2bf(a.x); o[1] = f2bf(a.y); o[2] = f2bf(a.z); o[3] = f2bf(a.w);
  o[4] = f2bf(b.x); o[5] = f2bf(b.y); o[6] = f2bf(b.z); o[7] = f2bf(b.w);
  *(u16x8*)(dst + (size_t)c * 512 + lane * 8) = o;
}

// per-code weighted-window output table O[4096][256]; also inits flag + cnt
__global__ __launch_bounds__(256)
void k_code_out(const float* __restrict__ W, float* __restrict__ Otab,
                int* __restrict__ flag, int* __restrict__ cnt) {
  if (threadIdx.x == 0) {
    if (blockIdx.x == 0) *flag = 0;
    if (blockIdx.x < NST) cnt[blockIdx.x] = 0;
  }
  const int lane = threadIdx.x & 63;
  const int code = blockIdx.x * 4 + (threadIdx.x >> 6);
  float w = 0.f;
  if (lane < 41) {
    int d = lane - KNN;
    int idx = code + d;
    bool left  = (code - KNN) < 0;
    bool valid = (idx >= 0) && (idx < NVEC) && (!left || (d < KNN));
    w = valid ? expf(-0.5f * (float)(d * d)) : 0.f;
  }
  float ssum = w;
  #pragma unroll
  for (int off = 32; off >= 1; off >>= 1) ssum += __shfl_xor(ssum, off);
  float inv = 1.f / ssum;

  float4 acc = {0.f, 0.f, 0.f, 0.f};
  #pragma unroll
  for (int d = 0; d < 41; d++) {
    float wd = __shfl(w, d);
    int idx = code + d - KNN;
    idx = idx < 0 ? 0 : (idx >= NVEC ? NVEC - 1 : idx);
    float4 wr = *(const float4*)(W + (size_t)idx * EDIM + lane * 4);
    acc.x += wd * wr.x; acc.y += wd * wr.y;
    acc.z += wd * wr.z; acc.w += wd * wr.w;
  }
  acc.x *= inv; acc.y *= inv; acc.z *= inv; acc.w *= inv;
  *(float4*)(Otab + (size_t)code * EDIM + lane * 4) = acc;
}

// ---- tiled GEMM + per-tile top-3 argmin stats + fused last-arriver pick ----
// 128x128 tile, 8 K-steps of 32. Both operands pre-tiled bf16 fragment-order;
// staged via global_load_lds (1KB contiguous per wave-instr), double-buffered
// 32KB LDS, one barrier per K-step. Partials go to out[] (first 512B of each
// sample row). The 32nd block to finish a sample tile (device-scope counter,
// release/acquire fences) reduces + refines + writes the final 128 rows —
// its partials/Otab reads are L2-hot on its own XCD (all 32 blocks of an st
// share one swz-chunk). Order-independent: no waits, no dispatch assumptions.
#define STAGE(kk_, buf_) { \
  gload16(wsrc + (kk_) * 4096 + (wv * 2    ) * 512 + lane * 8, wls + (buf_) * 4096 + (wv * 2    ) * 512); \
  gload16(wsrc + (kk_) * 4096 + (wv * 2 + 1) * 512 + lane * 8, wls + (buf_) * 4096 + (wv * 2 + 1) * 512); \
  gload16(xsrc + (kk_) * 4096 + (wv * 2    ) * 512 + lane * 8, xls + (buf_) * 4096 + (wv * 2    ) * 512); \
  gload16(xsrc + (kk_) * 4096 + (wv * 2 + 1) * 512 + lane * 8, xls + (buf_) * 4096 + (wv * 2 + 1) * 512); \
}

__global__ __launch_bounds__(256, 4)
void k_gemm(const float* __restrict__ x, const float* __restrict__ W,
            const unsigned short* __restrict__ Wt,
            const unsigned short* __restrict__ Xt,
            const float* __restrict__ Otab,
            float* __restrict__ outp, int* __restrict__ flag,
            int* __restrict__ cnt) {
  __shared__ unsigned short wls[2 * 8 * 512];   // 16 KB (double-buffered W step)
  __shared__ unsigned short xls[2 * 8 * 512];   // 16 KB (double-buffered x step)
  __shared__ int s_last;

  const int t = threadIdx.x, lane = t & 63, wv = t >> 6;
  const int lm = lane & 15, lq = lane >> 4;
  const int wm = wv >> 1, wn = wv & 1;

  const int bid = blockIdx.x;
  const int swz = (bid & 7) * (GGRID / 8) + (bid >> 3);  // XCD-contiguous
  const int st = swz >> 5, ct = swz & 31;

  const unsigned short* wsrc = Wt + (size_t)ct * (NKK * 8 * 512);
  const unsigned short* xsrc = Xt + (size_t)st * (NKK * 8 * 512);

  f32x4 acc[4][4];
  #pragma unroll
  for (int i = 0; i < 4; i++)
    #pragma unroll
    for (int j = 0; j < 4; j++) acc[i][j] = (f32x4){0.f, 0.f, 0.f, 0.f};

  STAGE(0, 0)
  __syncthreads();   // vmcnt(0) drain: buf0 ready

  #pragma unroll
  for (int kk = 0; kk < NKK; kk++) {
    const int buf = kk & 1;
    if (kk < NKK - 1) STAGE(kk + 1, buf ^ 1)
    s16x8 av[4], bv[4];
    #pragma unroll
    for (int i = 0; i < 4; i++)
      av[i] = *(const s16x8*)(wls + buf * 4096 + (wn * 4 + i) * 512 + lane * 8);
    #pragma unroll
    for (int j = 0; j < 4; j++)
      bv[j] = *(const s16x8*)(xls + buf * 4096 + (wm * 4 + j) * 512 + lane * 8);
    #pragma unroll
    for (int i = 0; i < 4; i++)
      #pragma unroll
      for (int j = 0; j < 4; j++)
        acc[i][j] = __builtin_amdgcn_mfma_f32_16x16x32_bf16(av[i], bv[j], acc[i][j], 0, 0, 0);
    __syncthreads();   // next buf staged; this buf's reads done
  }

  // ---- layout self-check: every block checks its own quadrant (so every
  // sample tile's flag view is covered by its own 32 blocks) ----
  {
    float ex = dot_np((const float4*)(x + (size_t)(st * TS + wm * 64 + lm) * EDIM),
                      (const float4*)(W + (size_t)(ct * TC + wn * 64 + lq * 4 + 1) * EDIM));
    if (fabsf(ex - acc[0][0][1]) > 2.0f) *flag = 1;
  }

  // ---- per-sample (m1,r1 | m2,r2 | m3) over this wave's 64 codes ----
  float m1a[4], m2a[4], m3a[4]; int r1a[4], r2a[4];
  #pragma unroll
  for (int j = 0; j < 4; j++) {
    float m1 = FINF, m2 = FINF, m3 = FINF; int r1 = 0, r2 = 0;
    #pragma unroll
    for (int i = 0; i < 4; i++)
      #pragma unroll
      for (int r = 0; r < 4; r++) {
        float v = acc[i][j][r];
        int rowc = ct * TC + wn * 64 + i * 16 + lq * 4 + r;  // ascending per lane
        INS3(v, rowc)
      }
    // reduce over the 4 lq lanes of this lm (lane, ^16, ^32, ^48)
    #pragma unroll
    for (int off = 16; off <= 32; off <<= 1) {
      float o1 = __shfl_xor(m1, off);
      float o2 = __shfl_xor(m2, off);
      float o3 = __shfl_xor(m3, off);
      int   q1 = __shfl_xor(r1, off);
      int   q2 = __shfl_xor(r2, off);
      INS3(o1, q1)
      INS3(o2, q2)
      m3 = fminf(m3, fmaxf(m2, o3));   // o3 can never reach top-2
    }
    m1a[j] = m1; m2a[j] = m2; m3a[j] = m3; r1a[j] = r1; r2a[j] = r2;
  }

  // merge wn halves via LDS (alias wls: all reads done), write partials
  float4* smrg = (float4*)wls;
  if (wn == 1 && lq == 0) {
    #pragma unroll
    for (int j = 0; j < 4; j++)
      smrg[wm * 64 + j * 16 + lm] =
          make_float4(m1a[j], m2a[j], m3a[j],
                      __int_as_float(r1a[j] | (r2a[j] << 12)));
  }
  __syncthreads();
  if (wn == 0 && lq == 0) {
    #pragma unroll
    for (int j = 0; j < 4; j++) {
      const int srow = wm * 64 + j * 16 + lm;
      float4 o = smrg[srow];
      float m1 = m1a[j], m2 = m2a[j], m3 = m3a[j];
      int r1 = r1a[j], r2 = r2a[j];
      int op = __float_as_int(o.w);
      int q1 = op & 0xFFF, q2 = (op >> 12) & 0xFFF;
      INS3(o.x, q1)       // wn1 rows larger: strict '<' keeps wn0 on ties
      INS3(o.y, q2)
      m3 = fminf(m3, fmaxf(m2, o.z));
      // partials live in out[]: sample b's row, first 32 float4s (read then
      // overwritten by this tile's picking block)
      ((float4*)outp)[(size_t)(st * TS + srow) * (EDIM / 4) + ct] =
          make_float4(m1, m2, m3, __int_as_float(r1 | (r2 << 12)));
    }
  }

  // ---- completion protocol: release stores, count arrivals ----
  __threadfence();                       // release: partials + flag visible
  __syncthreads();
  if (t == 0) s_last = atomicAdd(cnt + st, 1);
  __syncthreads();
  if (s_last != NCT - 1) return;
  __threadfence();                       // acquire: see all 32 blocks' stores

  // ---- pick for this sample tile: 4 waves x 32 samples ----
  // Screen error E: |screen(r) - d(r)| <= E, MARGIN >= 2E. Candidate set
  // {r : screen(r) <= th} is enumerated by {r1(c), r2(c)} plus rescans of
  // tiles with m3 <= th (~never). Singleton: exactly one contributor with
  // m1<=th and none with m2<=th -> its r1 IS the argmin, no dots needed.
  const bool ok = (*flag == 0);
  const int cc = lane & 31;              // both halves hold the same contributor
  const int b0 = st * TS + wv * 32;
  float4 p = ((const float4*)outp)[(size_t)b0 * (EDIM / 4) + cc];
  for (int u = 0; u < 32; u++) {
    const int b = b0 + u;
    float4 pc = p;
    if (u < 31) p = ((const float4*)outp)[(size_t)(b + 1) * (EDIM / 4) + cc];
    float m1 = pc.x, m2 = pc.y, m3 = pc.z;
    int rows = __float_as_int(pc.w);
    int r1 = rows & 0xFFF, r2 = (rows >> 12) & 0xFFF;

    float gm = m1;   // halves duplicate -> 5 steps suffice
    #pragma unroll
    for (int off = 16; off >= 1; off >>= 1) gm = fminf(gm, __shfl_xor(gm, off));
    const float th = gm + MARGIN;

    unsigned long long bm1 = __ballot(lane < 32 && m1 <= th);
    unsigned long long bm2 = __ballot(lane < 32 && m2 <= th);

    int id;
    if (ok && __popcll(bm1) == 1 && bm2 == 0ull) {
      // easy path (~60-70%): singleton candidate. No dots.
      id = __shfl(r1, (int)__builtin_ctzll(bm1));
    } else {
      const float4* xq = (const float4*)(x + (size_t)b * EDIM);
      unsigned long long best = 0xFFFFFFFFFFFFFFFFull;
      if (ok) {
        // one candidate dot per lane: lower half r1, upper half r2
        const int  myr = (lane < 32) ? r1 : r2;
        const bool mym = (lane < 32) ? (m1 <= th) : (m2 <= th);
        if (mym) {
          float d = dot_np(xq, (const float4*)(W + (size_t)myr * EDIM));
          best = ((unsigned long long)fenc(d) << 32) | (unsigned)myr;
        }
        // tiles with 3+ near-min rows -> exact rescan (~never)
        unsigned long long db = __ballot(lane < 32 && m3 <= th);
        while (db) {
          int dc = __builtin_ctzll(db); db &= db - 1;
          const int base = dc * TC;
          #pragma unroll
          for (int tt = 0; tt < 2; tt++) {
            int row = base + lane * 2 + tt;
            float d = dot_np(xq, (const float4*)(W + (size_t)row * EDIM));
            unsigned long long key = ((unsigned long long)fenc(d) << 32) | (unsigned)row;
            if (key < best) best = key;
          }
        }
      } else {
        // layout-bad fallback: full np-order scan
        for (int n = lane; n < NVEC; n += 64) {
          float d = dot_np(xq, (const float4*)(W + (size_t)n * EDIM));
          unsigned long long key = ((unsigned long long)fenc(d) << 32) | (unsigned)n;
          if (key < best) best = key;
        }
      }
      #pragma unroll
      for (int off = 32; off >= 1; off >>= 1) {
        unsigned long long o = __shfl_xor(best, off);
        if (o < best) best = o;
      }
      id = (int)(unsigned int)(best & 0xFFFFFFFFull);
    }

    float4 v = *(const float4*)(Otab + (size_t)id * EDIM + lane * 4);
    *(float4*)(outp + (size_t)b * EDIM + lane * 4) = v;
  }
}

extern "C" void kernel_launch(void* const* d_in, const int* in_sizes, int n_in,
                              void* d_out, int out_size, void* d_ws, size_t ws_size,
                              hipStream_t stream) {
  const float* x = (const float*)d_in[0];   // [32768,256] fp32
  const float* W = (const float*)d_in[1];   // [4096,256]  fp32
  float* out = (float*)d_out;

  char* ws = (char*)d_ws;
  unsigned short* Wt = (unsigned short*)ws;                 // 2 MB  (fragment-order bf16 W)
  unsigned short* Xt = (unsigned short*)(ws + (2u << 20));  // 16 MB (fragment-order bf16 x)
  float* Otab = (float*)(ws + (18u << 20));                 // 4 MB
  int* flag   = (int*)(ws + (22u << 20));                   // 4 B
  int* cnt    = (int*)(ws + (22u << 20) + 256);             // 256 ints

  k_tilecvt<<<512, 256, 0, stream>>>(W, Wt);                // 2048 chunks
  k_tilecvt<<<4096, 256, 0, stream>>>(x, Xt);               // 16384 chunks
  k_code_out<<<1024, 256, 0, stream>>>(W, Otab, flag, cnt);
  k_gemm<<<GGRID, 256, 0, stream>>>(x, W, Wt, Xt, Otab, out, flag, cnt);
}

// Round 9
// 611.226 us; speedup vs baseline: 2.3230x; 2.3230x over previous
//
#include <hip/hip_runtime.h>

#define BATCH 32768
#define NVEC  4096
#define EDIM  256
#define KNN   20

#define TS 128               // samples per gemm block
#define TC 128               // codes per gemm block
#define NCT (NVEC/TC)        // 32 code tiles
#define NST (BATCH/TS)       // 256 sample tiles
#define GGRID (NST*NCT)      // 8192 blocks
#define NKK 8                // K-steps of 32
#define MARGIN 2.0f          // > 2 * worst-case bf16 dot error (~0.8)
#define FINF   3.4e38f

typedef short          s16x8 __attribute__((ext_vector_type(8)));
typedef unsigned short u16x8 __attribute__((ext_vector_type(8)));
typedef float          f32x4 __attribute__((ext_vector_type(4)));

__device__ __forceinline__ unsigned short f2bf(float f) {
  unsigned int u = __float_as_uint(f);
  u += 0x7fffu + ((u >> 16) & 1u);   // RNE; inputs finite
  return (unsigned short)(u >> 16);
}

// monotone float->uint encoding: order-preserving over all finite floats
__device__ __forceinline__ unsigned int fenc(float f) {
  unsigned int u = __float_as_uint(f);
  return (u & 0x80000000u) ? ~u : (u | 0x80000000u);
}

// fp32 k-ascending dot — EXACT source pattern of the passing kernels
// (same compiler contraction => same rounding class as the reference).
__device__ __forceinline__ float dot_np(const float4* __restrict__ xq,
                                        const float4* __restrict__ wq) {
  float d = 0.f;
  for (int k = 0; k < EDIM / 4; k++) {
    float4 a4 = xq[k], b4 = wq[k];
    d += a4.x * b4.x;
    d += a4.y * b4.y;
    d += a4.z * b4.z;
    d += a4.w * b4.w;
  }
  return d;
}

__device__ __forceinline__ void gload16(const unsigned short* g, unsigned short* l) {
  __builtin_amdgcn_global_load_lds(
      (const __attribute__((address_space(1))) unsigned int*)g,
      (__attribute__((address_space(3))) unsigned int*)l, 16, 0, 0);
}

// streaming top-3 insert (values) + top-2 rows, branchless.
// strict '<': earlier-inserted row wins ties (set semantics safe either way).
#define INS3(v_, q_) { \
  float om1_ = m1, om2_ = m2; \
  m3 = fminf(m3, fmaxf(om2_, (v_))); \
  m2 = fminf(om2_, fmaxf(om1_, (v_))); \
  bool lt1_ = (v_) < om1_, lt2_ = (v_) < om2_; \
  r2 = lt1_ ? r1 : (lt2_ ? (q_) : r2); \
  r1 = lt1_ ? (q_) : r1; \
  m1 = fminf(om1_, (v_)); \
}

// fp32 row-major [R][256] -> bf16 fragment-order tiles.
// chunk c = ((rowtile*8 + kk)*8 + g): 1KB holding rows rowtile*128+g*16+lm,
// cols kk*32+lq*8 (8 bf16 per lane, lane = lq*16+lm). One wave per chunk.
__global__ __launch_bounds__(256)
void k_tilecvt(const float* __restrict__ src, unsigned short* __restrict__ dst) {
  const int lane = threadIdx.x & 63, wv = threadIdx.x >> 6;
  const int lm = lane & 15, lq = lane >> 4;
  const int c = blockIdx.x * 4 + wv;
  const int rt = c >> 6, kk = (c >> 3) & 7, g = c & 7;
  const int row = rt * 128 + g * 16 + lm;
  const float* p = src + (size_t)row * EDIM + kk * 32 + lq * 8;
  float4 a = ((const float4*)p)[0], b = ((const float4*)p)[1];
  u16x8 o;
  o[0] = f2bf(a.x); o[1] = f2bf(a.y); o[2] = f2bf(a.z); o[3] = f2bf(a.w);
  o[4] = f2bf(b.x); o[5] = f2bf(b.y); o[6] = f2bf(b.z); o[7] = f2bf(b.w);
  *(u16x8*)(dst + (size_t)c * 512 + lane * 8) = o;
}

// per-code weighted-window output table O[4096][256]; also inits flag
__global__ __launch_bounds__(256)
void k_code_out(const float* __restrict__ W, float* __restrict__ Otab,
                int* __restrict__ flag) {
  if (blockIdx.x == 0 && threadIdx.x == 0) *flag = 0;
  const int lane = threadIdx.x & 63;
  const int code = blockIdx.x * 4 + (threadIdx.x >> 6);
  float w = 0.f;
  if (lane < 41) {
    int d = lane - KNN;
    int idx = code + d;
    bool left  = (code - KNN) < 0;
    bool valid = (idx >= 0) && (idx < NVEC) && (!left || (d < KNN));
    w = valid ? expf(-0.5f * (float)(d * d)) : 0.f;
  }
  float ssum = w;
  #pragma unroll
  for (int off = 32; off >= 1; off >>= 1) ssum += __shfl_xor(ssum, off);
  float inv = 1.f / ssum;

  float4 acc = {0.f, 0.f, 0.f, 0.f};
  #pragma unroll
  for (int d = 0; d < 41; d++) {
    float wd = __shfl(w, d);
    int idx = code + d - KNN;
    idx = idx < 0 ? 0 : (idx >= NVEC ? NVEC - 1 : idx);
    float4 wr = *(const float4*)(W + (size_t)idx * EDIM + lane * 4);
    acc.x += wd * wr.x; acc.y += wd * wr.y;
    acc.z += wd * wr.z; acc.w += wd * wr.w;
  }
  acc.x *= inv; acc.y *= inv; acc.z *= inv; acc.w *= inv;
  *(float4*)(Otab + (size_t)code * EDIM + lane * 4) = acc;
}

// ---- tiled GEMM + per-tile top-3 argmin stats (round-6 version, verbatim) ----
#define STAGE(kk_, buf_) { \
  gload16(wsrc + (kk_) * 4096 + (wv * 2    ) * 512 + lane * 8, wls + (buf_) * 4096 + (wv * 2    ) * 512); \
  gload16(wsrc + (kk_) * 4096 + (wv * 2 + 1) * 512 + lane * 8, wls + (buf_) * 4096 + (wv * 2 + 1) * 512); \
  gload16(xsrc + (kk_) * 4096 + (wv * 2    ) * 512 + lane * 8, xls + (buf_) * 4096 + (wv * 2    ) * 512); \
  gload16(xsrc + (kk_) * 4096 + (wv * 2 + 1) * 512 + lane * 8, xls + (buf_) * 4096 + (wv * 2 + 1) * 512); \
}

__global__ __launch_bounds__(256, 4)
void k_gemm(const float* __restrict__ x, const float* __restrict__ W,
            const unsigned short* __restrict__ Wt,
            const unsigned short* __restrict__ Xt,
            float4* __restrict__ part, int* __restrict__ flag) {
  __shared__ unsigned short wls[2 * 8 * 512];   // 16 KB (double-buffered W step)
  __shared__ unsigned short xls[2 * 8 * 512];   // 16 KB (double-buffered x step)

  const int t = threadIdx.x, lane = t & 63, wv = t >> 6;
  const int lm = lane & 15, lq = lane >> 4;
  const int wm = wv >> 1, wn = wv & 1;

  const int bid = blockIdx.x;
  const int swz = (bid & 7) * (GGRID / 8) + (bid >> 3);  // XCD-contiguous
  const int st = swz >> 5, ct = swz & 31;

  const unsigned short* wsrc = Wt + (size_t)ct * (NKK * 8 * 512);
  const unsigned short* xsrc = Xt + (size_t)st * (NKK * 8 * 512);

  f32x4 acc[4][4];
  #pragma unroll
  for (int i = 0; i < 4; i++)
    #pragma unroll
    for (int j = 0; j < 4; j++) acc[i][j] = (f32x4){0.f, 0.f, 0.f, 0.f};

  STAGE(0, 0)
  __syncthreads();   // vmcnt(0) drain: buf0 ready

  #pragma unroll
  for (int kk = 0; kk < NKK; kk++) {
    const int buf = kk & 1;
    if (kk < NKK - 1) STAGE(kk + 1, buf ^ 1)
    s16x8 av[4], bv[4];
    #pragma unroll
    for (int i = 0; i < 4; i++)
      av[i] = *(const s16x8*)(wls + buf * 4096 + (wn * 4 + i) * 512 + lane * 8);
    #pragma unroll
    for (int j = 0; j < 4; j++)
      bv[j] = *(const s16x8*)(xls + buf * 4096 + (wm * 4 + j) * 512 + lane * 8);
    #pragma unroll
    for (int i = 0; i < 4; i++)
      #pragma unroll
      for (int j = 0; j < 4; j++)
        acc[i][j] = __builtin_amdgcn_mfma_f32_16x16x32_bf16(av[i], bv[j], acc[i][j], 0, 0, 0);
    __syncthreads();   // next buf staged; this buf's reads done
  }

  // ---- layout self-check (one block, all wave quadrants, transpose-detecting) ----
  if (swz == 0) {
    float ex = dot_np((const float4*)(x + (size_t)(wm * 64 + lm) * EDIM),
                      (const float4*)(W + (size_t)(wn * 64 + lq * 4 + 1) * EDIM));
    if (fabsf(ex - acc[0][0][1]) > 2.0f) *flag = 1;
  }

  // ---- per-sample (m1,r1 | m2,r2 | m3) over this wave's 64 codes ----
  float m1a[4], m2a[4], m3a[4]; int r1a[4], r2a[4];
  #pragma unroll
  for (int j = 0; j < 4; j++) {
    float m1 = FINF, m2 = FINF, m3 = FINF; int r1 = 0, r2 = 0;
    #pragma unroll
    for (int i = 0; i < 4; i++)
      #pragma unroll
      for (int r = 0; r < 4; r++) {
        float v = acc[i][j][r];
        int rowc = ct * TC + wn * 64 + i * 16 + lq * 4 + r;  // ascending per lane
        INS3(v, rowc)
      }
    // reduce over the 4 lq lanes of this lm (lane, ^16, ^32, ^48)
    #pragma unroll
    for (int off = 16; off <= 32; off <<= 1) {
      float o1 = __shfl_xor(m1, off);
      float o2 = __shfl_xor(m2, off);
      float o3 = __shfl_xor(m3, off);
      int   q1 = __shfl_xor(r1, off);
      int   q2 = __shfl_xor(r2, off);
      INS3(o1, q1)
      INS3(o2, q2)
      m3 = fminf(m3, fmaxf(m2, o3));   // o3 can never reach top-2
    }
    m1a[j] = m1; m2a[j] = m2; m3a[j] = m3; r1a[j] = r1; r2a[j] = r2;
  }

  // merge wn halves via LDS (alias wls: all reads done), write partials
  float4* smrg = (float4*)wls;
  if (wn == 1 && lq == 0) {
    #pragma unroll
    for (int j = 0; j < 4; j++)
      smrg[wm * 64 + j * 16 + lm] =
          make_float4(m1a[j], m2a[j], m3a[j],
                      __int_as_float(r1a[j] | (r2a[j] << 12)));
  }
  __syncthreads();
  if (wn == 0 && lq == 0) {
    #pragma unroll
    for (int j = 0; j < 4; j++) {
      const int srow = wm * 64 + j * 16 + lm;
      float4 o = smrg[srow];
      float m1 = m1a[j], m2 = m2a[j], m3 = m3a[j];
      int r1 = r1a[j], r2 = r2a[j];
      int op = __float_as_int(o.w);
      int q1 = op & 0xFFF, q2 = (op >> 12) & 0xFFF;
      INS3(o.x, q1)       // wn1 rows larger: strict '<' keeps wn0 on ties
      INS3(o.y, q2)
      m3 = fminf(m3, fmaxf(m2, o.z));
      // partials live in out[]: sample b's row, first 32 float4s (overwritten
      // by k_pick after it reads them)
      part[(size_t)(st * TS + srow) * (EDIM / 4) + ct] =
          make_float4(m1, m2, m3, __int_as_float(r1 | (r2 << 12)));
    }
  }
}

// ---- per-sample reduce + cooperative-dot refine + output ----
// Certificate (as round 6): every row with screen <= th is r1(c) or r2(c) of
// its tile unless that tile has m3 <= th (then full scan; ~0.03%). Easy path:
// singleton bm1, empty bm2 -> argmin is that r1, no dots. Hard path: collect
// candidate rows in LDS; each 16-lane group computes one candidate's np-order
// dot with WAVE-UNIFORM addresses (broadcast loads: ~5 lines/iter, not the
// 64-line/iter per-lane gather that made round-6's version 4 us/wave).
__global__ __launch_bounds__(512)
void k_pick(const float* __restrict__ x, const float* __restrict__ W,
            const float* __restrict__ Otab, const int* __restrict__ flag,
            float* __restrict__ out) {
  __shared__ int scand[8][64];   // candidate rows per wave
  const int lane = threadIdx.x & 63, wv = threadIdx.x >> 6;
  const int b = blockIdx.x * 8 + wv;
  const int c = lane & 31;   // both 32-lane halves hold the same contributor

  // partials were written into this sample's own out row (first 512B)
  float4 p = ((const float4*)out)[(size_t)b * (EDIM / 4) + c];
  float m1 = p.x, m2 = p.y, m3 = p.z;
  int rows = __float_as_int(p.w);
  int r1 = rows & 0xFFF, r2 = (rows >> 12) & 0xFFF;

  float gm = m1;   // halves duplicate -> 5 steps suffice
  #pragma unroll
  for (int off = 16; off >= 1; off >>= 1) gm = fminf(gm, __shfl_xor(gm, off));
  const float th = gm + MARGIN;

  const bool ok = (*flag == 0);
  unsigned long long bm1 = __ballot(lane < 32 && m1 <= th);
  unsigned long long bm2 = __ballot(lane < 32 && m2 <= th);
  unsigned long long bm3 = __ballot(lane < 32 && m3 <= th);

  int id;
  if (ok && __popcll(bm1) == 1 && bm2 == 0ull) {
    // easy path (~38%): singleton candidate. No dots.
    id = __shfl(r1, (int)__builtin_ctzll(bm1));
  } else if (ok && bm3 == 0ull) {
    // cooperative hard path: K candidates, 4 dots per pass (16 lanes each)
    const int n1 = (int)__popcll(bm1);
    const int K  = n1 + (int)__popcll(bm2);
    if (lane < 32) {
      unsigned long long pre = (1ull << lane) - 1;
      if (m1 <= th) scand[wv][(int)__popcll(bm1 & pre)] = r1;
      if (m2 <= th) scand[wv][n1 + (int)__popcll(bm2 & pre)] = r2;
    }
    const float4* xq = (const float4*)(x + (size_t)b * EDIM);
    unsigned long long best = 0xFFFFFFFFFFFFFFFFull;
    for (int base = 0; base < K; base += 4) {
      int ci = base + (lane >> 4);
      int r = scand[wv][ci < K ? ci : 0];
      float d = dot_np(xq, (const float4*)(W + (size_t)r * EDIM));
      unsigned long long key = ((unsigned long long)fenc(d) << 32) | (unsigned)r;
      if (ci < K && key < best) best = key;
    }
    #pragma unroll
    for (int off = 32; off >= 1; off >>= 1) {
      unsigned long long o = __shfl_xor(best, off);
      if (o < best) best = o;
    }
    id = (int)(unsigned int)(best & 0xFFFFFFFFull);
  } else {
    // m3-dirty (~0.03%) or layout-bad: full np-order scan (gather; rare)
    const float4* xq = (const float4*)(x + (size_t)b * EDIM);
    unsigned long long best = 0xFFFFFFFFFFFFFFFFull;
    for (int n = lane; n < NVEC; n += 64) {
      float d = dot_np(xq, (const float4*)(W + (size_t)n * EDIM));
      unsigned long long key = ((unsigned long long)fenc(d) << 32) | (unsigned)n;
      if (key < best) best = key;
    }
    #pragma unroll
    for (int off = 32; off >= 1; off >>= 1) {
      unsigned long long o = __shfl_xor(best, off);
      if (o < best) best = o;
    }
    id = (int)(unsigned int)(best & 0xFFFFFFFFull);
  }

  float4 v = *(const float4*)(Otab + (size_t)id * EDIM + lane * 4);
  *(float4*)(out + (size_t)b * EDIM + lane * 4) = v;
}

extern "C" void kernel_launch(void* const* d_in, const int* in_sizes, int n_in,
                              void* d_out, int out_size, void* d_ws, size_t ws_size,
                              hipStream_t stream) {
  const float* x = (const float*)d_in[0];   // [32768,256] fp32
  const float* W = (const float*)d_in[1];   // [4096,256]  fp32
  float* out = (float*)d_out;

  char* ws = (char*)d_ws;
  unsigned short* Wt = (unsigned short*)ws;                 // 2 MB  (fragment-order bf16 W)
  unsigned short* Xt = (unsigned short*)(ws + (2u << 20));  // 16 MB (fragment-order bf16 x)
  float* Otab = (float*)(ws + (18u << 20));                 // 4 MB
  int* flag   = (int*)(ws + (22u << 20));                   // 4 B

  k_tilecvt<<<512, 256, 0, stream>>>(W, Wt);                // 2048 chunks
  k_tilecvt<<<4096, 256, 0, stream>>>(x, Xt);               // 16384 chunks
  k_code_out<<<1024, 256, 0, stream>>>(W, Otab, flag);
  k_gemm<<<GGRID, 256, 0, stream>>>(x, W, Wt, Xt, (float4*)out, flag);
  k_pick<<<BATCH / 8, 512, 0, stream>>>(x, W, Otab, flag, out);
}

// Round 11
// 253.964 us; speedup vs baseline: 5.5907x; 2.4067x over previous
//
#include <hip/hip_runtime.h>

#define BATCH 32768
#define NVEC  4096
#define EDIM  256
#define KNN   20

#define TS 128               // samples per gemm block
#define TC 128               // codes per gemm block
#define NCT (NVEC/TC)        // 32 code tiles
#define NST (BATCH/TS)       // 256 sample tiles
#define GGRID (NST*NCT)      // 8192 blocks
#define NKK 8                // K-steps of 32
#define MARGIN 2.0f          // > 2 * worst-case bf16 dot error (~0.8)
#define FINF   3.4e38f

typedef short          s16x8 __attribute__((ext_vector_type(8)));
typedef unsigned short u16x8 __attribute__((ext_vector_type(8)));
typedef float          f32x4 __attribute__((ext_vector_type(4)));

__device__ __forceinline__ unsigned short f2bf(float f) {
  unsigned int u = __float_as_uint(f);
  u += 0x7fffu + ((u >> 16) & 1u);   // RNE; inputs finite
  return (unsigned short)(u >> 16);
}

// monotone float->uint encoding: order-preserving over all finite floats
__device__ __forceinline__ unsigned int fenc(float f) {
  unsigned int u = __float_as_uint(f);
  return (u & 0x80000000u) ? ~u : (u | 0x80000000u);
}

// fp32 k-ascending dot — EXACT source pattern of the passing kernels
// (same compiler contraction => same rounding class as the reference).
__device__ __forceinline__ float dot_np(const float4* __restrict__ xq,
                                        const float4* __restrict__ wq) {
  float d = 0.f;
  for (int k = 0; k < EDIM / 4; k++) {
    float4 a4 = xq[k], b4 = wq[k];
    d += a4.x * b4.x;
    d += a4.y * b4.y;
    d += a4.z * b4.z;
    d += a4.w * b4.w;
  }
  return d;
}

__device__ __forceinline__ void gload16(const unsigned short* g, unsigned short* l) {
  __builtin_amdgcn_global_load_lds(
      (const __attribute__((address_space(1))) unsigned int*)g,
      (__attribute__((address_space(3))) unsigned int*)l, 16, 0, 0);
}

// streaming top-3 insert (values) + top-2 rows, branchless.
// strict '<': earlier-inserted row wins ties (set semantics safe either way).
#define INS3(v_, q_) { \
  float om1_ = m1, om2_ = m2; \
  m3 = fminf(m3, fmaxf(om2_, (v_))); \
  m2 = fminf(om2_, fmaxf(om1_, (v_))); \
  bool lt1_ = (v_) < om1_, lt2_ = (v_) < om2_; \
  r2 = lt1_ ? r1 : (lt2_ ? (q_) : r2); \
  r1 = lt1_ ? (q_) : r1; \
  m1 = fminf(om1_, (v_)); \
}

// fp32 row-major [R][256] -> bf16 fragment-order tiles.
// chunk c = ((rowtile*8 + kk)*8 + g): 1KB holding rows rowtile*128+g*16+lm,
// cols kk*32+lq*8 (8 bf16 per lane, lane = lq*16+lm). One wave per chunk.
__global__ __launch_bounds__(256)
void k_tilecvt(const float* __restrict__ src, unsigned short* __restrict__ dst) {
  const int lane = threadIdx.x & 63, wv = threadIdx.x >> 6;
  const int lm = lane & 15, lq = lane >> 4;
  const int c = blockIdx.x * 4 + wv;
  const int rt = c >> 6, kk = (c >> 3) & 7, g = c & 7;
  const int row = rt * 128 + g * 16 + lm;
  const float* p = src + (size_t)row * EDIM + kk * 32 + lq * 8;
  float4 a = ((const float4*)p)[0], b = ((const float4*)p)[1];
  u16x8 o;
  o[0] = f2bf(a.x); o[1] = f2bf(a.y); o[2] = f2bf(a.z); o[3] = f2bf(a.w);
  o[4] = f2bf(b.x); o[5] = f2bf(b.y); o[6] = f2bf(b.z); o[7] = f2bf(b.w);
  *(u16x8*)(dst + (size_t)c * 512 + lane * 8) = o;
}

// per-code weighted-window output table O[4096][256]; also inits flag
__global__ __launch_bounds__(256)
void k_code_out(const float* __restrict__ W, float* __restrict__ Otab,
                int* __restrict__ flag) {
  if (blockIdx.x == 0 && threadIdx.x == 0) *flag = 0;
  const int lane = threadIdx.x & 63;
  const int code = blockIdx.x * 4 + (threadIdx.x >> 6);
  float w = 0.f;
  if (lane < 41) {
    int d = lane - KNN;
    int idx = code + d;
    bool left  = (code - KNN) < 0;
    bool valid = (idx >= 0) && (idx < NVEC) && (!left || (d < KNN));
    w = valid ? expf(-0.5f * (float)(d * d)) : 0.f;
  }
  float ssum = w;
  #pragma unroll
  for (int off = 32; off >= 1; off >>= 1) ssum += __shfl_xor(ssum, off);
  float inv = 1.f / ssum;

  float4 acc = {0.f, 0.f, 0.f, 0.f};
  #pragma unroll
  for (int d = 0; d < 41; d++) {
    float wd = __shfl(w, d);
    int idx = code + d - KNN;
    idx = idx < 0 ? 0 : (idx >= NVEC ? NVEC - 1 : idx);
    float4 wr = *(const float4*)(W + (size_t)idx * EDIM + lane * 4);
    acc.x += wd * wr.x; acc.y += wd * wr.y;
    acc.z += wd * wr.z; acc.w += wd * wr.w;
  }
  acc.x *= inv; acc.y *= inv; acc.z *= inv; acc.w *= inv;
  *(float4*)(Otab + (size_t)code * EDIM + lane * 4) = acc;
}

// ---- tiled GEMM + per-tile top-3 argmin stats (round-6 version, verbatim) ----
#define STAGE(kk_, buf_) { \
  gload16(wsrc + (kk_) * 4096 + (wv * 2    ) * 512 + lane * 8, wls + (buf_) * 4096 + (wv * 2    ) * 512); \
  gload16(wsrc + (kk_) * 4096 + (wv * 2 + 1) * 512 + lane * 8, wls + (buf_) * 4096 + (wv * 2 + 1) * 512); \
  gload16(xsrc + (kk_) * 4096 + (wv * 2    ) * 512 + lane * 8, xls + (buf_) * 4096 + (wv * 2    ) * 512); \
  gload16(xsrc + (kk_) * 4096 + (wv * 2 + 1) * 512 + lane * 8, xls + (buf_) * 4096 + (wv * 2 + 1) * 512); \
}

__global__ __launch_bounds__(256, 4)
void k_gemm(const float* __restrict__ x, const float* __restrict__ W,
            const unsigned short* __restrict__ Wt,
            const unsigned short* __restrict__ Xt,
            float4* __restrict__ part, int* __restrict__ flag) {
  __shared__ unsigned short wls[2 * 8 * 512];   // 16 KB (double-buffered W step)
  __shared__ unsigned short xls[2 * 8 * 512];   // 16 KB (double-buffered x step)

  const int t = threadIdx.x, lane = t & 63, wv = t >> 6;
  const int lm = lane & 15, lq = lane >> 4;
  const int wm = wv >> 1, wn = wv & 1;

  const int bid = blockIdx.x;
  const int swz = (bid & 7) * (GGRID / 8) + (bid >> 3);  // XCD-contiguous
  const int st = swz >> 5, ct = swz & 31;

  const unsigned short* wsrc = Wt + (size_t)ct * (NKK * 8 * 512);
  const unsigned short* xsrc = Xt + (size_t)st * (NKK * 8 * 512);

  f32x4 acc[4][4];
  #pragma unroll
  for (int i = 0; i < 4; i++)
    #pragma unroll
    for (int j = 0; j < 4; j++) acc[i][j] = (f32x4){0.f, 0.f, 0.f, 0.f};

  STAGE(0, 0)
  __syncthreads();   // vmcnt(0) drain: buf0 ready

  #pragma unroll
  for (int kk = 0; kk < NKK; kk++) {
    const int buf = kk & 1;
    if (kk < NKK - 1) STAGE(kk + 1, buf ^ 1)
    s16x8 av[4], bv[4];
    #pragma unroll
    for (int i = 0; i < 4; i++)
      av[i] = *(const s16x8*)(wls + buf * 4096 + (wn * 4 + i) * 512 + lane * 8);
    #pragma unroll
    for (int j = 0; j < 4; j++)
      bv[j] = *(const s16x8*)(xls + buf * 4096 + (wm * 4 + j) * 512 + lane * 8);
    #pragma unroll
    for (int i = 0; i < 4; i++)
      #pragma unroll
      for (int j = 0; j < 4; j++)
        acc[i][j] = __builtin_amdgcn_mfma_f32_16x16x32_bf16(av[i], bv[j], acc[i][j], 0, 0, 0);
    __syncthreads();   // next buf staged; this buf's reads done
  }

  // ---- layout self-check (one block, all wave quadrants, transpose-detecting) ----
  if (swz == 0) {
    float ex = dot_np((const float4*)(x + (size_t)(wm * 64 + lm) * EDIM),
                      (const float4*)(W + (size_t)(wn * 64 + lq * 4 + 1) * EDIM));
    if (fabsf(ex - acc[0][0][1]) > 2.0f) *flag = 1;
  }

  // ---- per-sample (m1,r1 | m2,r2 | m3) over this wave's 64 codes ----
  float m1a[4], m2a[4], m3a[4]; int r1a[4], r2a[4];
  #pragma unroll
  for (int j = 0; j < 4; j++) {
    float m1 = FINF, m2 = FINF, m3 = FINF; int r1 = 0, r2 = 0;
    #pragma unroll
    for (int i = 0; i < 4; i++)
      #pragma unroll
      for (int r = 0; r < 4; r++) {
        float v = acc[i][j][r];
        int rowc = ct * TC + wn * 64 + i * 16 + lq * 4 + r;  // ascending per lane
        INS3(v, rowc)
      }
    // reduce over the 4 lq lanes of this lm (lane, ^16, ^32, ^48)
    #pragma unroll
    for (int off = 16; off <= 32; off <<= 1) {
      float o1 = __shfl_xor(m1, off);
      float o2 = __shfl_xor(m2, off);
      float o3 = __shfl_xor(m3, off);
      int   q1 = __shfl_xor(r1, off);
      int   q2 = __shfl_xor(r2, off);
      INS3(o1, q1)
      INS3(o2, q2)
      m3 = fminf(m3, fmaxf(m2, o3));   // o3 can never reach top-2
    }
    m1a[j] = m1; m2a[j] = m2; m3a[j] = m3; r1a[j] = r1; r2a[j] = r2;
  }

  // merge wn halves via LDS (alias wls: all reads done), write partials
  float4* smrg = (float4*)wls;
  if (wn == 1 && lq == 0) {
    #pragma unroll
    for (int j = 0; j < 4; j++)
      smrg[wm * 64 + j * 16 + lm] =
          make_float4(m1a[j], m2a[j], m3a[j],
                      __int_as_float(r1a[j] | (r2a[j] << 12)));
  }
  __syncthreads();
  if (wn == 0 && lq == 0) {
    #pragma unroll
    for (int j = 0; j < 4; j++) {
      const int srow = wm * 64 + j * 16 + lm;
      float4 o = smrg[srow];
      float m1 = m1a[j], m2 = m2a[j], m3 = m3a[j];
      int r1 = r1a[j], r2 = r2a[j];
      int op = __float_as_int(o.w);
      int q1 = op & 0xFFF, q2 = (op >> 12) & 0xFFF;
      INS3(o.x, q1)       // wn1 rows larger: strict '<' keeps wn0 on ties
      INS3(o.y, q2)
      m3 = fminf(m3, fmaxf(m2, o.z));
      // partials live in out[]: sample b's row, first 32 float4s (overwritten
      // by k_pick after it reads them)
      part[(size_t)(st * TS + srow) * (EDIM / 4) + ct] =
          make_float4(m1, m2, m3, __int_as_float(r1 | (r2 << 12)));
    }
  }
}

// ---- per-sample reduce + cooperative-dot refine + output ----
// Certificate: every row with screen <= th is r1(c) or r2(c) of its tile,
// except rows of tiles with m3 <= th; those tiles get a bounded 128-row
// rescan (2 gather-dots/lane — the round-5/6 machinery; ~0.3% of samples).
// Easy path: singleton bm1, empty bm2 -> argmin is that r1, no dots.
// Common hard path: candidates in LDS; each 16-lane group computes one
// candidate's np-order dot with WAVE-UNIFORM addresses (broadcast loads).
// Full 4096-row scan only on layout-bad flag.
__global__ __launch_bounds__(512)
void k_pick(const float* __restrict__ x, const float* __restrict__ W,
            const float* __restrict__ Otab, const int* __restrict__ flag,
            float* __restrict__ out) {
  __shared__ int scand[8][64];   // candidate rows per wave
  const int lane = threadIdx.x & 63, wv = threadIdx.x >> 6;
  const int b = blockIdx.x * 8 + wv;
  const int c = lane & 31;   // both 32-lane halves hold the same contributor

  // partials were written into this sample's own out row (first 512B)
  float4 p = ((const float4*)out)[(size_t)b * (EDIM / 4) + c];
  float m1 = p.x, m2 = p.y, m3 = p.z;
  int rows = __float_as_int(p.w);
  int r1 = rows & 0xFFF, r2 = (rows >> 12) & 0xFFF;

  float gm = m1;   // halves duplicate -> 5 steps suffice
  #pragma unroll
  for (int off = 16; off >= 1; off >>= 1) gm = fminf(gm, __shfl_xor(gm, off));
  const float th = gm + MARGIN;

  const bool ok = (*flag == 0);
  unsigned long long bm1 = __ballot(lane < 32 && m1 <= th);
  unsigned long long bm2 = __ballot(lane < 32 && m2 <= th);
  unsigned long long bm3 = __ballot(lane < 32 && m3 <= th);

  int id;
  if (ok && __popcll(bm1) == 1 && bm2 == 0ull) {
    // easy path (~38%): singleton candidate. No dots.
    id = __shfl(r1, (int)__builtin_ctzll(bm1));
  } else if (ok) {
    // cooperative hard path: K candidates, 4 dots per pass (16 lanes each)
    const int n1 = (int)__popcll(bm1);
    const int K  = n1 + (int)__popcll(bm2);
    if (lane < 32) {
      unsigned long long pre = (1ull << lane) - 1;
      if (m1 <= th) scand[wv][(int)__popcll(bm1 & pre)] = r1;
      if (m2 <= th) scand[wv][n1 + (int)__popcll(bm2 & pre)] = r2;
    }
    const float4* xq = (const float4*)(x + (size_t)b * EDIM);
    unsigned long long best = 0xFFFFFFFFFFFFFFFFull;
    for (int base = 0; base < K; base += 4) {
      int ci = base + (lane >> 4);
      int r = scand[wv][ci < K ? ci : 0];
      float d = dot_np(xq, (const float4*)(W + (size_t)r * EDIM));
      unsigned long long key = ((unsigned long long)fenc(d) << 32) | (unsigned)r;
      if (ci < K && key < best) best = key;
    }
    // tiles with 3+ near-min rows: bounded 128-row rescan (2 rows/lane)
    unsigned long long db = bm3;
    while (db) {
      int cc = __builtin_ctzll(db); db &= db - 1;
      const int base = cc * TC;
      #pragma unroll
      for (int tt = 0; tt < 2; tt++) {
        int row = base + lane * 2 + tt;
        float d = dot_np(xq, (const float4*)(W + (size_t)row * EDIM));
        unsigned long long key = ((unsigned long long)fenc(d) << 32) | (unsigned)row;
        if (key < best) best = key;
      }
    }
    #pragma unroll
    for (int off = 32; off >= 1; off >>= 1) {
      unsigned long long o = __shfl_xor(best, off);
      if (o < best) best = o;
    }
    id = (int)(unsigned int)(best & 0xFFFFFFFFull);
  } else {
    // layout-bad fallback: full np-order scan
    const float4* xq = (const float4*)(x + (size_t)b * EDIM);
    unsigned long long best = 0xFFFFFFFFFFFFFFFFull;
    for (int n = lane; n < NVEC; n += 64) {
      float d = dot_np(xq, (const float4*)(W + (size_t)n * EDIM));
      unsigned long long key = ((unsigned long long)fenc(d) << 32) | (unsigned)n;
      if (key < best) best = key;
    }
    #pragma unroll
    for (int off = 32; off >= 1; off >>= 1) {
      unsigned long long o = __shfl_xor(best, off);
      if (o < best) best = o;
    }
    id = (int)(unsigned int)(best & 0xFFFFFFFFull);
  }

  float4 v = *(const float4*)(Otab + (size_t)id * EDIM + lane * 4);
  *(float4*)(out + (size_t)b * EDIM + lane * 4) = v;
}

extern "C" void kernel_launch(void* const* d_in, const int* in_sizes, int n_in,
                              void* d_out, int out_size, void* d_ws, size_t ws_size,
                              hipStream_t stream) {
  const float* x = (const float*)d_in[0];   // [32768,256] fp32
  const float* W = (const float*)d_in[1];   // [4096,256]  fp32
  float* out = (float*)d_out;

  char* ws = (char*)d_ws;
  unsigned short* Wt = (unsigned short*)ws;                 // 2 MB  (fragment-order bf16 W)
  unsigned short* Xt = (unsigned short*)(ws + (2u << 20));  // 16 MB (fragment-order bf16 x)
  float* Otab = (float*)(ws + (18u << 20));                 // 4 MB
  int* flag   = (int*)(ws + (22u << 20));                   // 4 B

  k_tilecvt<<<512, 256, 0, stream>>>(W, Wt);                // 2048 chunks
  k_tilecvt<<<4096, 256, 0, stream>>>(x, Xt);               // 16384 chunks
  k_code_out<<<1024, 256, 0, stream>>>(W, Otab, flag);
  k_gemm<<<GGRID, 256, 0, stream>>>(x, W, Wt, Xt, (float4*)out, flag);
  k_pick<<<BATCH / 8, 512, 0, stream>>>(x, W, Otab, flag, out);
}

// Round 12
// 235.194 us; speedup vs baseline: 6.0369x; 1.0798x over previous
//
#include <hip/hip_runtime.h>

#define BATCH 32768
#define NVEC  4096
#define EDIM  256
#define KNN   20

#define TS 128               // samples per gemm block
#define TC 128               // codes per gemm block
#define NCT (NVEC/TC)        // 32 code tiles
#define NST (BATCH/TS)       // 256 sample tiles
#define GGRID (NST*NCT)      // 8192 blocks
#define NKK 8                // K-steps of 32
#define MARGIN 2.0f          // > 2 * worst-case bf16 dot error (~0.8)
#define FINF   3.4e38f

typedef short          s16x8 __attribute__((ext_vector_type(8)));
typedef unsigned short u16x8 __attribute__((ext_vector_type(8)));
typedef float          f32x4 __attribute__((ext_vector_type(4)));

__device__ __forceinline__ unsigned short f2bf(float f) {
  unsigned int u = __float_as_uint(f);
  u += 0x7fffu + ((u >> 16) & 1u);   // RNE; inputs finite
  return (unsigned short)(u >> 16);
}

// monotone float->uint encoding: order-preserving over all finite floats
__device__ __forceinline__ unsigned int fenc(float f) {
  unsigned int u = __float_as_uint(f);
  return (u & 0x80000000u) ? ~u : (u | 0x80000000u);
}

// fp32 k-ascending dot — EXACT source pattern of the passing kernels
// (same compiler contraction => same rounding class as the reference).
__device__ __forceinline__ float dot_np(const float4* __restrict__ xq,
                                        const float4* __restrict__ wq) {
  float d = 0.f;
  for (int k = 0; k < EDIM / 4; k++) {
    float4 a4 = xq[k], b4 = wq[k];
    d += a4.x * b4.x;
    d += a4.y * b4.y;
    d += a4.z * b4.z;
    d += a4.w * b4.w;
  }
  return d;
}

__device__ __forceinline__ void gload16(const unsigned short* g, unsigned short* l) {
  __builtin_amdgcn_global_load_lds(
      (const __attribute__((address_space(1))) unsigned int*)g,
      (__attribute__((address_space(3))) unsigned int*)l, 16, 0, 0);
}

// ---- fused prep: W->bf16 tiles | x->bf16 tiles | Otab + flag init ----
// tilecvt chunk c = ((rowtile*8 + kk)*8 + g): 1KB holding rows
// rowtile*128+g*16+lm, cols kk*32+lq*8 (lane = lq*16+lm). One wave per chunk.
__global__ __launch_bounds__(256)
void k_prep(const float* __restrict__ x, const float* __restrict__ W,
            unsigned short* __restrict__ Wt, unsigned short* __restrict__ Xt,
            float* __restrict__ Otab, int* __restrict__ flag) {
  const int bid = blockIdx.x;
  const int t = threadIdx.x;
  const int lane = t & 63, wv = t >> 6;

  if (bid < 4608) {
    // tile-convert: [0,512) -> W (2048 chunks), [512,4608) -> x (16384 chunks)
    const bool isW = bid < 512;
    const float* src = isW ? W : x;
    unsigned short* dst = isW ? Wt : Xt;
    const int c = (isW ? bid : bid - 512) * 4 + wv;
    const int lm = lane & 15, lq = lane >> 4;
    const int rt = c >> 6, kk = (c >> 3) & 7, g = c & 7;
    const int row = rt * 128 + g * 16 + lm;
    const float* p = src + (size_t)row * EDIM + kk * 32 + lq * 8;
    float4 a = ((const float4*)p)[0], b = ((const float4*)p)[1];
    u16x8 o;
    o[0] = f2bf(a.x); o[1] = f2bf(a.y); o[2] = f2bf(a.z); o[3] = f2bf(a.w);
    o[4] = f2bf(b.x); o[5] = f2bf(b.y); o[6] = f2bf(b.z); o[7] = f2bf(b.w);
    *(u16x8*)(dst + (size_t)c * 512 + lane * 8) = o;
    return;
  }

  // per-code weighted-window output table O[4096][256]
  if (bid == 4608 && t == 0) *flag = 0;
  const int code = (bid - 4608) * 4 + (t >> 6);
  float w = 0.f;
  if (lane < 41) {
    int d = lane - KNN;
    int idx = code + d;
    bool left  = (code - KNN) < 0;
    bool valid = (idx >= 0) && (idx < NVEC) && (!left || (d < KNN));
    w = valid ? expf(-0.5f * (float)(d * d)) : 0.f;
  }
  float ssum = w;
  #pragma unroll
  for (int off = 32; off >= 1; off >>= 1) ssum += __shfl_xor(ssum, off);
  float inv = 1.f / ssum;

  float4 acc = {0.f, 0.f, 0.f, 0.f};
  #pragma unroll
  for (int d = 0; d < 41; d++) {
    float wd = __shfl(w, d);
    int idx = code + d - KNN;
    idx = idx < 0 ? 0 : (idx >= NVEC ? NVEC - 1 : idx);
    float4 wr = *(const float4*)(W + (size_t)idx * EDIM + lane * 4);
    acc.x += wd * wr.x; acc.y += wd * wr.y;
    acc.z += wd * wr.z; acc.w += wd * wr.w;
  }
  acc.x *= inv; acc.y *= inv; acc.z *= inv; acc.w *= inv;
  *(float4*)(Otab + (size_t)code * EDIM + lane * 4) = acc;
}

// ---- tiled GEMM + per-half-tile candidate bitmap ----
// Hot loop identical to the 115-us round-6 kernel. Epilogue replaced:
// instead of streaming top-3 (INS3, ~10 VALU/value), compute per-sample
// tile-min (1 fmin/value + wn-half LDS exchange), then a 64-bit bitmap of
// rows with screen <= m1_tile + MARGIN (~3 VALU/value). Bitmap is the
// COMPLETE candidate set for the pick certificate: for any tile with
// m1 <= gm+MARGIN, gm+M <= m1_tile+M, so no candidate row is ever missed
// and k_pick needs no rescan path.
// Partial per (sample, tile, half): uint4 {m1_tile, bm_lo, bm_hi, 0} at
// part[sample*64 + wn*32 + ct] — exactly the sample's 1KB out row.
#define STAGE(kk_, buf_) { \
  gload16(wsrc + (kk_) * 4096 + (wv * 2    ) * 512 + lane * 8, wls + (buf_) * 4096 + (wv * 2    ) * 512); \
  gload16(wsrc + (kk_) * 4096 + (wv * 2 + 1) * 512 + lane * 8, wls + (buf_) * 4096 + (wv * 2 + 1) * 512); \
  gload16(xsrc + (kk_) * 4096 + (wv * 2    ) * 512 + lane * 8, xls + (buf_) * 4096 + (wv * 2    ) * 512); \
  gload16(xsrc + (kk_) * 4096 + (wv * 2 + 1) * 512 + lane * 8, xls + (buf_) * 4096 + (wv * 2 + 1) * 512); \
}

__global__ __launch_bounds__(256, 4)
void k_gemm(const float* __restrict__ x, const float* __restrict__ W,
            const unsigned short* __restrict__ Wt,
            const unsigned short* __restrict__ Xt,
            uint4* __restrict__ part, int* __restrict__ flag) {
  __shared__ unsigned short wls[2 * 8 * 512];   // 16 KB (double-buffered W step)
  __shared__ unsigned short xls[2 * 8 * 512];   // 16 KB (double-buffered x step)

  const int t = threadIdx.x, lane = t & 63, wv = t >> 6;
  const int lm = lane & 15, lq = lane >> 4;
  const int wm = wv >> 1, wn = wv & 1;

  const int bid = blockIdx.x;
  const int swz = (bid & 7) * (GGRID / 8) + (bid >> 3);  // XCD-contiguous
  const int st = swz >> 5, ct = swz & 31;

  const unsigned short* wsrc = Wt + (size_t)ct * (NKK * 8 * 512);
  const unsigned short* xsrc = Xt + (size_t)st * (NKK * 8 * 512);

  f32x4 acc[4][4];
  #pragma unroll
  for (int i = 0; i < 4; i++)
    #pragma unroll
    for (int j = 0; j < 4; j++) acc[i][j] = (f32x4){0.f, 0.f, 0.f, 0.f};

  STAGE(0, 0)
  __syncthreads();   // vmcnt(0) drain: buf0 ready

  #pragma unroll
  for (int kk = 0; kk < NKK; kk++) {
    const int buf = kk & 1;
    if (kk < NKK - 1) STAGE(kk + 1, buf ^ 1)
    s16x8 av[4], bv[4];
    #pragma unroll
    for (int i = 0; i < 4; i++)
      av[i] = *(const s16x8*)(wls + buf * 4096 + (wn * 4 + i) * 512 + lane * 8);
    #pragma unroll
    for (int j = 0; j < 4; j++)
      bv[j] = *(const s16x8*)(xls + buf * 4096 + (wm * 4 + j) * 512 + lane * 8);
    #pragma unroll
    for (int i = 0; i < 4; i++)
      #pragma unroll
      for (int j = 0; j < 4; j++)
        acc[i][j] = __builtin_amdgcn_mfma_f32_16x16x32_bf16(av[i], bv[j], acc[i][j], 0, 0, 0);
    __syncthreads();   // next buf staged; this buf's reads done
  }

  // ---- layout self-check (one block, all wave quadrants, transpose-detecting) ----
  if (swz == 0) {
    float ex = dot_np((const float4*)(x + (size_t)(wm * 64 + lm) * EDIM),
                      (const float4*)(W + (size_t)(wn * 64 + lq * 4 + 1) * EDIM));
    if (fabsf(ex - acc[0][0][1]) > 2.0f) *flag = 1;
  }

  // ---- pass 1: per-sample min over this wave's 64 codes (half-tile) ----
  float m1h[4];
  #pragma unroll
  for (int j = 0; j < 4; j++) {
    float m = acc[0][j][0];
    #pragma unroll
    for (int i = 0; i < 4; i++)
      #pragma unroll
      for (int r = 0; r < 4; r++) m = fminf(m, acc[i][j][r]);
    m = fminf(m, __shfl_xor(m, 16));
    m = fminf(m, __shfl_xor(m, 32));   // all 4 lq lanes hold the half min
    m1h[j] = m;
  }

  // ---- exchange wn halves via LDS (alias wls: all reads done) -> tile min ----
  float* sm = (float*)wls;   // [2][128]
  if (lq == 0) {
    #pragma unroll
    for (int j = 0; j < 4; j++) sm[wn * 128 + wm * 64 + j * 16 + lm] = m1h[j];
  }
  __syncthreads();

  // ---- pass 2: bitmap of rows with screen <= m1_tile + MARGIN ----
  #pragma unroll
  for (int j = 0; j < 4; j++) {
    float mo = sm[(wn ^ 1) * 128 + wm * 64 + j * 16 + lm];
    float m1t = fminf(m1h[j], mo);
    float th = m1t + MARGIN;
    unsigned lo = 0u, hi = 0u;
    #pragma unroll
    for (int i = 0; i < 4; i++)
      #pragma unroll
      for (int r = 0; r < 4; r++) {
        // within-half row p = i*16 + lq*4 + r; i<2 -> lo word (compile-time)
        unsigned bit = (acc[i][j][r] <= th) ? 1u : 0u;
        if (i < 2) lo |= bit << (i * 16 + lq * 4 + r);
        else       hi |= bit << ((i - 2) * 16 + lq * 4 + r);
      }
    lo |= __shfl_xor(lo, 16); hi |= __shfl_xor(hi, 16);
    lo |= __shfl_xor(lo, 32); hi |= __shfl_xor(hi, 32);
    if (lq == 0) {
      int sample = st * TS + wm * 64 + j * 16 + lm;
      part[(size_t)sample * 64 + wn * 32 + ct] =
          make_uint4(__float_as_uint(m1t), lo, hi, 0u);
    }
  }
}

// ---- per-sample reduce + bitmap-driven refine + output ----
// Lane h (0..63) owns half-tile h: tile c = h&31, half = h>>5, with the
// TILE-level m1 (duplicated across the pair) and its half's 64-bit bitmap.
// Candidate set = union of bitmaps of half-tiles with m1 <= gm+MARGIN —
// complete by construction (no rescan path needed). K==1 -> answer with no
// dots. Else coop np-order dots (16 lanes per candidate, broadcast loads).
__global__ __launch_bounds__(512)
void k_pick(const float* __restrict__ x, const float* __restrict__ W,
            const float* __restrict__ Otab, const int* __restrict__ flag,
            float* __restrict__ out) {
  __shared__ int scand[8][128];   // candidate rows per wave
  const int lane = threadIdx.x & 63, wv = threadIdx.x >> 6;
  const int b = blockIdx.x * 8 + wv;

  // partials live in this sample's own out row (64 x uint4 = 1KB, coalesced)
  uint4 p = ((const uint4*)out)[(size_t)b * 64 + lane];
  float m1 = __uint_as_float(p.x);

  float gm = m1;
  #pragma unroll
  for (int off = 32; off >= 1; off >>= 1) gm = fminf(gm, __shfl_xor(gm, off));
  const float th = gm + MARGIN;

  const bool ok = (*flag == 0);

  // enumerate candidates from active half-tiles' bitmaps
  int K = 0;
  unsigned long long act = __ballot(m1 <= th);
  while (act) {
    int h = (int)__builtin_ctzll(act); act &= act - 1;
    unsigned lo2 = __shfl(p.y, h), hi2 = __shfl(p.z, h);
    unsigned long long hbm = ((unsigned long long)hi2 << 32) | (unsigned long long)lo2;
    bool mine = (hbm >> lane) & 1ull;
    unsigned long long mb = __ballot(mine);
    if (mine) {
      int pos = K + (int)__popcll(mb & ((1ull << lane) - 1ull));
      if (pos < 128) scand[wv][pos] = (h & 31) * TC + (h >> 5) * 64 + lane;
    }
    K += (int)__popcll(mb);
  }

  int id;
  if (ok && K == 1) {
    // easy path (~38%): single candidate is provably the argmin. No dots.
    id = scand[wv][0];
  } else if (ok && K <= 128) {
    // coop hard path: 4 candidate dots per pass (16 lanes each, uniform addr)
    const float4* xq = (const float4*)(x + (size_t)b * EDIM);
    unsigned long long best = 0xFFFFFFFFFFFFFFFFull;
    for (int base = 0; base < K; base += 4) {
      int ci = base + (lane >> 4);
      int r = scand[wv][ci < K ? ci : 0];
      float d = dot_np(xq, (const float4*)(W + (size_t)r * EDIM));
      unsigned long long key = ((unsigned long long)fenc(d) << 32) | (unsigned)r;
      if (ci < K && key < best) best = key;
    }
    #pragma unroll
    for (int off = 32; off >= 1; off >>= 1) {
      unsigned long long o = __shfl_xor(best, off);
      if (o < best) best = o;
    }
    id = (int)(unsigned int)(best & 0xFFFFFFFFull);
  } else {
    // layout-bad (or pathological K): full np-order scan
    const float4* xq = (const float4*)(x + (size_t)b * EDIM);
    unsigned long long best = 0xFFFFFFFFFFFFFFFFull;
    for (int n = lane; n < NVEC; n += 64) {
      float d = dot_np(xq, (const float4*)(W + (size_t)n * EDIM));
      unsigned long long key = ((unsigned long long)fenc(d) << 32) | (unsigned)n;
      if (key < best) best = key;
    }
    #pragma unroll
    for (int off = 32; off >= 1; off >>= 1) {
      unsigned long long o = __shfl_xor(best, off);
      if (o < best) best = o;
    }
    id = (int)(unsigned int)(best & 0xFFFFFFFFull);
  }

  float4 v = *(const float4*)(Otab + (size_t)id * EDIM + lane * 4);
  *(float4*)(out + (size_t)b * EDIM + lane * 4) = v;
}

extern "C" void kernel_launch(void* const* d_in, const int* in_sizes, int n_in,
                              void* d_out, int out_size, void* d_ws, size_t ws_size,
                              hipStream_t stream) {
  const float* x = (const float*)d_in[0];   // [32768,256] fp32
  const float* W = (const float*)d_in[1];   // [4096,256]  fp32
  float* out = (float*)d_out;

  char* ws = (char*)d_ws;
  unsigned short* Wt = (unsigned short*)ws;                 // 2 MB  (fragment-order bf16 W)
  unsigned short* Xt = (unsigned short*)(ws + (2u << 20));  // 16 MB (fragment-order bf16 x)
  float* Otab = (float*)(ws + (18u << 20));                 // 4 MB
  int* flag   = (int*)(ws + (22u << 20));                   // 4 B

  k_prep<<<5632, 256, 0, stream>>>(x, W, Wt, Xt, Otab, flag);
  k_gemm<<<GGRID, 256, 0, stream>>>(x, W, Wt, Xt, (uint4*)out, flag);
  k_pick<<<BATCH / 8, 512, 0, stream>>>(x, W, Otab, flag, out);
}